// Round 5
// baseline (510.994 us; speedup 1.0000x reference)
//
#include <hip/hip_runtime.h>
#include <hip/hip_bf16.h>
#include <math.h>

typedef unsigned int uint;
typedef unsigned short ushort;

typedef __attribute__((ext_vector_type(8))) short bf16x8;
typedef __attribute__((ext_vector_type(4))) float f32x4;

// ---------- small helpers ----------
__device__ __forceinline__ float bf2f(uint u) {
    return __uint_as_float(u << 16);
}
__device__ __forceinline__ float bf2f_lo(uint u) {   // low bf16 -> f32 (1 op)
    return __uint_as_float(u << 16);
}
__device__ __forceinline__ float bf2f_hi(uint u) {   // high bf16 -> f32 (1 op)
    return __uint_as_float(u & 0xffff0000u);
}
__device__ __forceinline__ ushort f2bf(float f) {
    uint u = __float_as_uint(f);
    uint rounding = 0x7fffu + ((u >> 16) & 1u);   // round-to-nearest-even
    return (ushort)((u + rounding) >> 16);
}
__device__ __forceinline__ float elu(float x) {
    return x > 0.f ? x : expm1f(x);
}

// ---------- degree histogram ----------
__global__ void count_kernel(const int* __restrict__ dst, int E, int* __restrict__ cnt) {
    int i = blockIdx.x * blockDim.x + threadIdx.x;
    int stride = gridDim.x * blockDim.x;
    for (; i < E; i += stride) atomicAdd(&cnt[dst[i]], 1);
}

// ---------- exclusive scan over cnt (3-phase) ----------
__global__ void scan1_kernel(const int* __restrict__ cnt, int NN, int* __restrict__ partials) {
    __shared__ int sh[256];
    int i = blockIdx.x * 256 + threadIdx.x;
    sh[threadIdx.x] = (i < NN) ? cnt[i] : 0;
    __syncthreads();
    for (int s = 128; s > 0; s >>= 1) {
        if (threadIdx.x < s) sh[threadIdx.x] += sh[threadIdx.x + s];
        __syncthreads();
    }
    if (threadIdx.x == 0) partials[blockIdx.x] = sh[0];
}

__global__ void scan2_kernel(const int* __restrict__ partials, int nb, int* __restrict__ pscan) {
    if (threadIdx.x == 0) {
        int run = 0;
        for (int b = 0; b < nb; ++b) { pscan[b] = run; run += partials[b]; }
    }
}

__global__ void scan3_kernel(const int* __restrict__ cnt, int NN, const int* __restrict__ pscan,
                             int* __restrict__ offs, int* __restrict__ cursor,
                             float* __restrict__ dinv) {
    __shared__ int sh[256];
    int t = threadIdx.x;
    int i = blockIdx.x * 256 + t;
    int v = (i < NN) ? cnt[i] : 0;
    sh[t] = v;
    __syncthreads();
    for (int d = 1; d < 256; d <<= 1) {
        int x = (t >= d) ? sh[t - d] : 0;
        __syncthreads();
        sh[t] += x;
        __syncthreads();
    }
    int incl = sh[t];
    int excl = incl - v;
    int base = pscan[blockIdx.x];
    if (i < NN) {
        offs[i]   = base + excl;
        cursor[i] = base + excl;
        dinv[i]   = rsqrtf((float)v + 1.0f);   // +1 self-loop; always >= 1
        if (i == NN - 1) offs[NN] = base + incl;
    }
}

// ---------- bucket edges by dst, XCD-partitioned ----------
__global__ __launch_bounds__(256) void scatter_kernel(const int* __restrict__ src,
                                                      const int* __restrict__ dst, int E,
                                                      int* __restrict__ cursor,
                                                      int* __restrict__ ssrc, int NN) {
    int grp = blockIdx.x & 7;
    int per = (NN + 7) >> 3;
    int lo = grp * per;
    int hi = min(NN, lo + per);
    int bid = blockIdx.x >> 3;
    int nb  = gridDim.x >> 3;
    int i = bid * blockDim.x + threadIdx.x;
    int stride = nb * blockDim.x;
    for (; i < E; i += stride) {
        int d = dst[i];
        if (d >= lo && d < hi) {
            int pos = atomicAdd(&cursor[d], 1);
            ssrc[pos] = src[i];
        }
    }
}

// ---------- graph boundaries via binary search on sorted batch ----------
__global__ void gstart_kernel(const int* __restrict__ batch, int NN, int NG,
                              int* __restrict__ gstart) {
    int g = blockIdx.x * blockDim.x + threadIdx.x;
    if (g > NG) return;
    int lo = 0, hi = NN;
    while (lo < hi) {
        int mid = (lo + hi) >> 1;
        if (batch[mid] < g) lo = mid + 1; else hi = mid;
    }
    gstart[g] = lo;
}

// ---------- W1T(bf16)[n][k] = W1[k][n], 64x64 tiles via LDS ----------
__global__ __launch_bounds__(256) void wtrans_kernel(const float* __restrict__ W,
                                                     ushort* __restrict__ WT) {
    __shared__ float T[64][68];
    int b = blockIdx.x;                 // 0..15
    int kt = (b >> 2) * 64, nt = (b & 3) * 64;
    int t = threadIdx.x;
    int r = t >> 4, c4 = (t & 15) * 4;
    #pragma unroll
    for (int h = 0; h < 4; ++h) {
        int rr = r + h * 16;
        float4 v = *reinterpret_cast<const float4*>(&W[(size_t)(kt + rr) * 256 + nt + c4]);
        *reinterpret_cast<float4*>(&T[rr][c4]) = v;
    }
    __syncthreads();
    int nr = t >> 2, ks = (t & 3) * 16;
    uint o[8];
    #pragma unroll
    for (int i = 0; i < 16; i += 2) {
        float f0 = T[ks + i][nr];
        float f1 = T[ks + i + 1][nr];
        o[i >> 1] = (uint)f2bf(f0) | ((uint)f2bf(f1) << 16);
    }
    size_t base = (size_t)(nt + nr) * 256 + kt + ks;
    *reinterpret_cast<uint4*>(&WT[base])     = make_uint4(o[0], o[1], o[2], o[3]);
    *reinterpret_cast<uint4*>(&WT[base + 8]) = make_uint4(o[4], o[5], o[6], o[7]);
}

// ---------- GEMM1 via MFMA: H1s(bf16)[M,256] = dinv[m] * (X @ W1) ----------
#define G1_STRIDE 40   // ushorts per LDS row (80B = 20 banks; 16B-aligned frag reads)
__global__ __launch_bounds__(256) void gemm1_mfma_kernel(const float* __restrict__ X,
                                                         const ushort* __restrict__ W1T,
                                                         const float* __restrict__ dinv,
                                                         ushort* __restrict__ H1, int M) {
    __shared__ ushort Xs[64 * G1_STRIDE];
    __shared__ ushort Ws[256 * G1_STRIDE];
    __shared__ float  Dvs[64];
    int t = threadIdx.x;
    int row0 = blockIdx.x * 64;
    int lane = t & 63;
    int w = t >> 6;
    int lr = lane & 15;     // row/col within fragment
    int lg = lane >> 4;     // k-group (8 contiguous k per lane)

    if (t < 64) {
        int grow = row0 + t;
        Dvs[t] = (grow < M) ? dinv[grow] : 0.f;
    }

    f32x4 acc[4][4];
    #pragma unroll
    for (int j = 0; j < 4; ++j)
        #pragma unroll
        for (int i = 0; i < 4; ++i)
            acc[j][i] = (f32x4){0.f, 0.f, 0.f, 0.f};

    for (int k0 = 0; k0 < 256; k0 += 32) {
        #pragma unroll
        for (int h = 0; h < 2; ++h) {
            int u = t + h * 256;
            int row = u >> 3;
            int kq = (u & 7) * 4;
            int grow = row0 + row;
            float4 v = make_float4(0.f, 0.f, 0.f, 0.f);
            if (grow < M) v = *reinterpret_cast<const float4*>(&X[(size_t)grow * 256 + k0 + kq]);
            uint lo = (uint)f2bf(v.x) | ((uint)f2bf(v.y) << 16);
            uint hi = (uint)f2bf(v.z) | ((uint)f2bf(v.w) << 16);
            *reinterpret_cast<uint2*>(&Xs[row * G1_STRIDE + kq]) = make_uint2(lo, hi);
        }
        #pragma unroll
        for (int h = 0; h < 4; ++h) {
            int u = t + h * 256;
            int n = u >> 2;
            int seg = u & 3;
            uint4 wv = *reinterpret_cast<const uint4*>(&W1T[(size_t)n * 256 + k0 + seg * 8]);
            *reinterpret_cast<uint4*>(&Ws[n * G1_STRIDE + seg * 8]) = wv;
        }
        __syncthreads();
        bf16x8 wf[4], xf[4];
        #pragma unroll
        for (int j = 0; j < 4; ++j)
            wf[j] = *reinterpret_cast<const bf16x8*>(&Ws[(w * 64 + j * 16 + lr) * G1_STRIDE + lg * 8]);
        #pragma unroll
        for (int i = 0; i < 4; ++i)
            xf[i] = *reinterpret_cast<const bf16x8*>(&Xs[(i * 16 + lr) * G1_STRIDE + lg * 8]);
        #pragma unroll
        for (int j = 0; j < 4; ++j)
            #pragma unroll
            for (int i = 0; i < 4; ++i)
                acc[j][i] = __builtin_amdgcn_mfma_f32_16x16x32_bf16(wf[j], xf[i], acc[j][i], 0, 0, 0);
        __syncthreads();
    }

    #pragma unroll
    for (int mi = 0; mi < 4; ++mi) {
        int grow = row0 + mi * 16 + lr;
        float dv = Dvs[mi * 16 + lr];
        bool ok = grow < M;
        #pragma unroll
        for (int nj = 0; nj < 4; ++nj) {
            f32x4 a = acc[nj][mi];
            uint lo = (uint)f2bf(a[0] * dv) | ((uint)f2bf(a[1] * dv) << 16);
            uint hi = (uint)f2bf(a[2] * dv) | ((uint)f2bf(a[3] * dv) << 16);
            if (ok) {
                int col = w * 64 + nj * 16 + lg * 4;
                *reinterpret_cast<uint2*>(&H1[(size_t)grow * 256 + col]) = make_uint2(lo, hi);
            }
        }
    }
}

// ---------- layer-1 aggregation, feature-sliced & XCD-partitioned ----------
// group g = blockIdx&7 -> XCD g (round-robin dispatch heuristic); handles
// features [32g, 32g+32) for ALL nodes. Slice of H1 = 3.2MB -> L2-resident,
// so the 1.6M random edge-gathers run at L2 bandwidth.
// Per wave: one node; lane = e(3b) x f(3b): 8 edge slots x 8 feature nibbles.
// One global_load_dwordx2 serves 8 edges. Writes act1 (bf16, +b1, ELU).
__global__ __launch_bounds__(256) void agg1_slice_kernel(
    const ushort* __restrict__ H1, const int* __restrict__ offs, const int* __restrict__ ssrc,
    const float* __restrict__ dinv, const float* __restrict__ b1,
    ushort* __restrict__ A1, int NN) {
    int g = blockIdx.x & 7;
    int node = (blockIdx.x >> 3) * 4 + (threadIdx.x >> 6);
    if (node >= NN) return;
    int lane = threadIdx.x & 63;
    int e = lane >> 3;            // edge slot 0..7
    int f = lane & 7;             // feature nibble 0..7
    int c0 = g * 32 + f * 4;      // feature base
    const ushort* H1c = H1 + c0;
    int beg = offs[node], end = offs[node + 1];
    float acc0 = 0.f, acc1 = 0.f, acc2 = 0.f, acc3 = 0.f;
    int i = beg + e;
    for (; i + 8 < end; i += 16) {       // 2 edges in flight per lane
        int s0 = ssrc[i], s1 = ssrc[i + 8];
        uint2 p0 = *reinterpret_cast<const uint2*>(H1c + (size_t)s0 * 256);
        uint2 p1 = *reinterpret_cast<const uint2*>(H1c + (size_t)s1 * 256);
        acc0 += bf2f_lo(p0.x) + bf2f_lo(p1.x);
        acc1 += bf2f_hi(p0.x) + bf2f_hi(p1.x);
        acc2 += bf2f_lo(p0.y) + bf2f_lo(p1.y);
        acc3 += bf2f_hi(p0.y) + bf2f_hi(p1.y);
    }
    for (; i < end; i += 8) {
        int s = ssrc[i];
        uint2 p = *reinterpret_cast<const uint2*>(H1c + (size_t)s * 256);
        acc0 += bf2f_lo(p.x);
        acc1 += bf2f_hi(p.x);
        acc2 += bf2f_lo(p.y);
        acc3 += bf2f_hi(p.y);
    }
    if (e == 0) {   // self loop (H1 pre-scaled by dinv[node])
        uint2 p = *reinterpret_cast<const uint2*>(H1c + (size_t)node * 256);
        acc0 += bf2f_lo(p.x);
        acc1 += bf2f_hi(p.x);
        acc2 += bf2f_lo(p.y);
        acc3 += bf2f_hi(p.y);
    }
    // reduce across the 8 edge slots (xor on bits 3,4,5)
    #pragma unroll
    for (int m = 8; m < 64; m <<= 1) {
        acc0 += __shfl_xor(acc0, m, 64);
        acc1 += __shfl_xor(acc1, m, 64);
        acc2 += __shfl_xor(acc2, m, 64);
        acc3 += __shfl_xor(acc3, m, 64);
    }
    if (e == 0) {
        float dn = dinv[node];
        float a0 = elu(fmaf(acc0, dn, b1[c0 + 0]));
        float a1 = elu(fmaf(acc1, dn, b1[c0 + 1]));
        float a2 = elu(fmaf(acc2, dn, b1[c0 + 2]));
        float a3 = elu(fmaf(acc3, dn, b1[c0 + 3]));
        uint lo = (uint)f2bf(a0) | ((uint)f2bf(a1) << 16);
        uint hi = (uint)f2bf(a2) | ((uint)f2bf(a3) << 16);
        *reinterpret_cast<uint2*>(&A1[(size_t)node * 256 + c0]) = make_uint2(lo, hi);
    }
}

// ---------- GEMM2 (256->10): H2s[node][c] = dinv[node] * (act1[node] @ W2)[c] ----------
__global__ __launch_bounds__(256) void gemm2_kernel(
    const ushort* __restrict__ A1, const float* __restrict__ dinv, const float* __restrict__ W2,
    float* __restrict__ H2, int NN) {
    int lane = threadIdx.x & 63;
    int node = blockIdx.x * 4 + (threadIdx.x >> 6);
    if (node >= NN) return;
    int col = lane * 4;
    uint2 p = *reinterpret_cast<const uint2*>(&A1[(size_t)node * 256 + col]);
    float a0 = bf2f_lo(p.x);
    float a1 = bf2f_hi(p.x);
    float a2 = bf2f_lo(p.y);
    float a3 = bf2f_hi(p.y);
    float hv = 0.f;
    #pragma unroll
    for (int c = 0; c < 10; ++c) {
        float q = a0 * W2[(col + 0) * 10 + c]
                + a1 * W2[(col + 1) * 10 + c]
                + a2 * W2[(col + 2) * 10 + c]
                + a3 * W2[(col + 3) * 10 + c];
        #pragma unroll
        for (int m = 1; m < 64; m <<= 1) q += __shfl_xor(q, m, 64);
        if (lane == c) hv = q;
    }
    if (lane < 10) H2[(size_t)node * 10 + lane] = dinv[node] * hv;
}

// ---------- layer-2 aggregation (+b2, ELU) -> per-node activations ----------
__global__ __launch_bounds__(256) void agg2_elu_kernel(
    const float* __restrict__ H2, const int* __restrict__ offs, const int* __restrict__ ssrc,
    const float* __restrict__ dinv, const float* __restrict__ b2,
    float* __restrict__ H2act, int NN) {
    int t = threadIdx.x;
    int node = blockIdx.x * 8 + (t >> 5);
    if (node >= NN) return;
    int sub = t & 31;
    int c = sub & 15;
    int e2 = sub >> 4;
    int beg = offs[node], end = offs[node + 1];
    float acc = 0.f;
    int i = beg + e2;
    for (; i + 6 < end; i += 8) {
        int s0 = ssrc[i], s1 = ssrc[i + 2], s2 = ssrc[i + 4], s3 = ssrc[i + 6];
        float h0 = H2[(size_t)s0 * 10 + c];
        float h1 = H2[(size_t)s1 * 10 + c];
        float h2 = H2[(size_t)s2 * 10 + c];
        float h3 = H2[(size_t)s3 * 10 + c];
        acc += (h0 + h1) + (h2 + h3);
    }
    for (; i < end; i += 2) acc += H2[(size_t)ssrc[i] * 10 + c];
    if (e2 == 0) acc += H2[(size_t)node * 10 + c];   // self loop (pre-scaled)
    acc += __shfl_xor(acc, 16, 64);
    if (sub < 10) {
        float dn = dinv[node];
        H2act[(size_t)node * 10 + c] = elu(fmaf(dn, acc, b2[c]));
    }
}

// ---------- per-graph mean pool + log_softmax (no atomics) ----------
__global__ __launch_bounds__(320) void pool_final_kernel(
    const float* __restrict__ H2act, const int* __restrict__ gstart,
    float* __restrict__ out, int NG) {
    __shared__ float red[32][10];
    __shared__ float m[10];
    __shared__ float s_lse;
    int g = blockIdx.x;
    int t = threadIdx.x;
    int grp = t / 10;
    int c = t - grp * 10;
    int lo = gstart[g], hi = gstart[g + 1];
    float acc = 0.f;
    if (grp < 32) {
        for (int n = lo + grp; n < hi; n += 32) acc += H2act[(size_t)n * 10 + c];
        red[grp][c] = acc;
    }
    __syncthreads();
    if (t < 10) {
        float s = 0.f;
        #pragma unroll
        for (int j = 0; j < 32; ++j) s += red[j][t];
        m[t] = s / fmaxf((float)(hi - lo), 1.0f);
    }
    __syncthreads();
    if (t == 0) {
        float mx = -1e30f;
        for (int c2 = 0; c2 < 10; ++c2) mx = fmaxf(mx, m[c2]);
        float s = 0.f;
        for (int c2 = 0; c2 < 10; ++c2) s += expf(m[c2] - mx);
        s_lse = logf(s) + mx;
    }
    __syncthreads();
    if (t < 10) out[g * 10 + t] = m[t] - s_lse;
}

extern "C" void kernel_launch(void* const* d_in, const int* in_sizes, int n_in,
                              void* d_out, int out_size, void* d_ws, size_t ws_size,
                              hipStream_t stream) {
    const float* x     = (const float*)d_in[0];
    const int*   eidx  = (const int*)d_in[1];
    const int*   batch = (const int*)d_in[2];
    const float* W1    = (const float*)d_in[3];
    const float* b1    = (const float*)d_in[4];
    const float* W2    = (const float*)d_in[5];
    const float* b2    = (const float*)d_in[6];

    int NN = in_sizes[0] / 256;     // 50000
    int E  = in_sizes[1] / 2;       // 1600000
    int NG = out_size / 10;         // 64
    const int* src = eidx;
    const int* dst = eidx + E;

    char* ws = (char*)d_ws;
    size_t off = 0;
    auto alloc = [&](size_t bytes) -> void* {
        void* p = ws + off;
        off += (bytes + 255) & ~((size_t)255);
        return p;
    };
    int*    cnt      = (int*)alloc((size_t)NN * 4);
    int*    offs     = (int*)alloc((size_t)(NN + 1) * 4);
    int*    cursor   = (int*)alloc((size_t)NN * 4);
    int*    partials = (int*)alloc(256 * 4);
    int*    pscan    = (int*)alloc(256 * 4);
    float*  dinv     = (float*)alloc((size_t)NN * 4);
    int*    gstart   = (int*)alloc((size_t)(NG + 1) * 4);
    ushort* W1T      = (ushort*)alloc((size_t)256 * 256 * 2);
    int*    ssrc     = (int*)alloc((size_t)E * 4);
    ushort* H1       = (ushort*)alloc((size_t)NN * 256 * 2);
    ushort* A1       = (ushort*)alloc((size_t)NN * 256 * 2);
    float*  H2       = (float*)alloc((size_t)NN * 10 * 4);
    float*  H2act    = (float*)alloc((size_t)NN * 10 * 4);

    hipMemsetAsync(cnt, 0, (size_t)NN * 4, stream);

    int nb = (NN + 255) / 256;
    count_kernel  <<<1024, 256, 0, stream>>>(dst, E, cnt);
    scan1_kernel  <<<nb, 256, 0, stream>>>(cnt, NN, partials);
    scan2_kernel  <<<1, 64, 0, stream>>>(partials, nb, pscan);
    scan3_kernel  <<<nb, 256, 0, stream>>>(cnt, NN, pscan, offs, cursor, dinv);
    scatter_kernel<<<2048, 256, 0, stream>>>(src, dst, E, cursor, ssrc, NN);
    gstart_kernel <<<1, 128, 0, stream>>>(batch, NN, NG, gstart);
    wtrans_kernel <<<16, 256, 0, stream>>>(W1, W1T);
    gemm1_mfma_kernel<<<(NN + 63) / 64, 256, 0, stream>>>(x, W1T, dinv, H1, NN);
    agg1_slice_kernel<<<((NN + 3) / 4) * 8, 256, 0, stream>>>(H1, offs, ssrc, dinv, b1, A1, NN);
    gemm2_kernel     <<<(NN + 3) / 4, 256, 0, stream>>>(A1, dinv, W2, H2, NN);
    agg2_elu_kernel  <<<(NN + 7) / 8, 256, 0, stream>>>(H2, offs, ssrc, dinv, b2, H2act, NN);
    pool_final_kernel<<<NG, 320, 0, stream>>>(H2act, gstart, (float*)d_out, NG);
}

// Round 6
// 337.403 us; speedup vs baseline: 1.5145x; 1.5145x over previous
//
#include <hip/hip_runtime.h>
#include <hip/hip_bf16.h>
#include <math.h>

typedef unsigned int uint;
typedef unsigned short ushort;

typedef __attribute__((ext_vector_type(8))) short bf16x8;
typedef __attribute__((ext_vector_type(4))) float f32x4;

// src-block sorting: edges within each dst segment are bucketed by src>>12
// (4096-node blocks, 13 used buckets, stride 16). All resident waves then
// sweep source blocks in near-lockstep -> gather working set ~2-6MB (L2-able)
// instead of the full 25.6MB H1 table.
#define SBLK_SHIFT 12
#define SBLK_STRIDE 16

// ---------- small helpers ----------
__device__ __forceinline__ float bf2f_lo(uint u) {
    return __uint_as_float(u << 16);
}
__device__ __forceinline__ float bf2f_hi(uint u) {
    return __uint_as_float(u & 0xffff0000u);
}
__device__ __forceinline__ ushort f2bf(float f) {
    uint u = __float_as_uint(f);
    uint rounding = 0x7fffu + ((u >> 16) & 1u);   // round-to-nearest-even
    return (ushort)((u + rounding) >> 16);
}
__device__ __forceinline__ float elu(float x) {
    return x > 0.f ? x : expm1f(x);
}

// ---------- per-(dst, src-block) histogram ----------
__global__ void count2_kernel(const int* __restrict__ src, const int* __restrict__ dst, int E,
                              int* __restrict__ cnt2) {
    int i = blockIdx.x * blockDim.x + threadIdx.x;
    int stride = gridDim.x * blockDim.x;
    for (; i < E; i += stride)
        atomicAdd(&cnt2[dst[i] * SBLK_STRIDE + (src[i] >> SBLK_SHIFT)], 1);
}

// ---------- exclusive scan over cnt2 (3-phase, M entries) ----------
__global__ void scan1_kernel(const int* __restrict__ cnt, int M, int* __restrict__ partials) {
    __shared__ int sh[256];
    int i = blockIdx.x * 256 + threadIdx.x;
    sh[threadIdx.x] = (i < M) ? cnt[i] : 0;
    __syncthreads();
    for (int s = 128; s > 0; s >>= 1) {
        if (threadIdx.x < s) sh[threadIdx.x] += sh[threadIdx.x + s];
        __syncthreads();
    }
    if (threadIdx.x == 0) partials[blockIdx.x] = sh[0];
}

// parallel exclusive scan of up to 4096 partials (256 thr x 16 each)
__global__ __launch_bounds__(256) void scan2_kernel(const int* __restrict__ partials, int nb,
                                                    int* __restrict__ pscan) {
    __shared__ int tsum[256];
    int t = threadIdx.x;
    int pref[16];
    int s = 0;
    #pragma unroll
    for (int j = 0; j < 16; ++j) {
        int idx = t * 16 + j;
        int v = (idx < nb) ? partials[idx] : 0;
        pref[j] = s;
        s += v;
    }
    tsum[t] = s;
    __syncthreads();
    for (int d = 1; d < 256; d <<= 1) {
        int x = (t >= d) ? tsum[t - d] : 0;
        __syncthreads();
        tsum[t] += x;
        __syncthreads();
    }
    int base = (t == 0) ? 0 : tsum[t - 1];
    #pragma unroll
    for (int j = 0; j < 16; ++j) {
        int idx = t * 16 + j;
        if (idx < nb) pscan[idx] = base + pref[j];
    }
}

__global__ void scan3_kernel(const int* __restrict__ cnt, int M, const int* __restrict__ pscan,
                             int* __restrict__ offs2, int* __restrict__ cursor2) {
    __shared__ int sh[256];
    int t = threadIdx.x;
    int i = blockIdx.x * 256 + t;
    int v = (i < M) ? cnt[i] : 0;
    sh[t] = v;
    __syncthreads();
    for (int d = 1; d < 256; d <<= 1) {
        int x = (t >= d) ? sh[t - d] : 0;
        __syncthreads();
        sh[t] += x;
        __syncthreads();
    }
    int excl = sh[t] - v;
    int base = pscan[blockIdx.x];
    if (i < M) {
        offs2[i]   = base + excl;
        cursor2[i] = base + excl;
    }
}

// ---------- per-node offsets + dinv from bucketed offsets ----------
__global__ void post_kernel(const int* __restrict__ offs2, int NN, int E,
                            int* __restrict__ offs, float* __restrict__ dinv) {
    int n = blockIdx.x * blockDim.x + threadIdx.x;
    if (n >= NN) return;
    int o = offs2[n * SBLK_STRIDE];
    int nxt = (n == NN - 1) ? E : offs2[(n + 1) * SBLK_STRIDE];
    offs[n] = o;
    dinv[n] = rsqrtf((float)(nxt - o) + 1.0f);
    if (n == NN - 1) offs[NN] = E;
}

// ---------- bucket edges by (dst, src-block), XCD-partitioned by dst ----------
__global__ __launch_bounds__(256) void scatter_kernel(const int* __restrict__ src,
                                                      const int* __restrict__ dst, int E,
                                                      int* __restrict__ cursor2,
                                                      int* __restrict__ ssrc, int NN) {
    int grp = blockIdx.x & 7;
    int per = (NN + 7) >> 3;
    int lo = grp * per;
    int hi = min(NN, lo + per);
    int bid = blockIdx.x >> 3;
    int nb  = gridDim.x >> 3;
    int i = bid * blockDim.x + threadIdx.x;
    int stride = nb * blockDim.x;
    for (; i < E; i += stride) {
        int d = dst[i];
        if (d >= lo && d < hi) {
            int s = src[i];
            int pos = atomicAdd(&cursor2[d * SBLK_STRIDE + (s >> SBLK_SHIFT)], 1);
            ssrc[pos] = s;
        }
    }
}

// ---------- graph boundaries via binary search on sorted batch ----------
__global__ void gstart_kernel(const int* __restrict__ batch, int NN, int NG,
                              int* __restrict__ gstart) {
    int g = blockIdx.x * blockDim.x + threadIdx.x;
    if (g > NG) return;
    int lo = 0, hi = NN;
    while (lo < hi) {
        int mid = (lo + hi) >> 1;
        if (batch[mid] < g) lo = mid + 1; else hi = mid;
    }
    gstart[g] = lo;
}

// ---------- W1T(bf16)[n][k] = W1[k][n], 64x64 tiles via LDS ----------
__global__ __launch_bounds__(256) void wtrans_kernel(const float* __restrict__ W,
                                                     ushort* __restrict__ WT) {
    __shared__ float T[64][68];
    int b = blockIdx.x;                 // 0..15
    int kt = (b >> 2) * 64, nt = (b & 3) * 64;
    int t = threadIdx.x;
    int r = t >> 4, c4 = (t & 15) * 4;
    #pragma unroll
    for (int h = 0; h < 4; ++h) {
        int rr = r + h * 16;
        float4 v = *reinterpret_cast<const float4*>(&W[(size_t)(kt + rr) * 256 + nt + c4]);
        *reinterpret_cast<float4*>(&T[rr][c4]) = v;
    }
    __syncthreads();
    int nr = t >> 2, ks = (t & 3) * 16;
    uint o[8];
    #pragma unroll
    for (int i = 0; i < 16; i += 2) {
        float f0 = T[ks + i][nr];
        float f1 = T[ks + i + 1][nr];
        o[i >> 1] = (uint)f2bf(f0) | ((uint)f2bf(f1) << 16);
    }
    size_t base = (size_t)(nt + nr) * 256 + kt + ks;
    *reinterpret_cast<uint4*>(&WT[base])     = make_uint4(o[0], o[1], o[2], o[3]);
    *reinterpret_cast<uint4*>(&WT[base + 8]) = make_uint4(o[4], o[5], o[6], o[7]);
}

// ---------- GEMM1 via MFMA: H1s(bf16)[M,256] = dinv[m] * (X @ W1) ----------
#define G1_STRIDE 40   // ushorts per LDS row (80B = 20 banks; 16B-aligned frag reads)
__global__ __launch_bounds__(256) void gemm1_mfma_kernel(const float* __restrict__ X,
                                                         const ushort* __restrict__ W1T,
                                                         const float* __restrict__ dinv,
                                                         ushort* __restrict__ H1, int M) {
    __shared__ ushort Xs[64 * G1_STRIDE];
    __shared__ ushort Ws[256 * G1_STRIDE];
    __shared__ float  Dvs[64];
    int t = threadIdx.x;
    int row0 = blockIdx.x * 64;
    int lane = t & 63;
    int w = t >> 6;
    int lr = lane & 15;     // row/col within fragment
    int lg = lane >> 4;     // k-group (8 contiguous k per lane)

    if (t < 64) {
        int grow = row0 + t;
        Dvs[t] = (grow < M) ? dinv[grow] : 0.f;
    }

    f32x4 acc[4][4];
    #pragma unroll
    for (int j = 0; j < 4; ++j)
        #pragma unroll
        for (int i = 0; i < 4; ++i)
            acc[j][i] = (f32x4){0.f, 0.f, 0.f, 0.f};

    for (int k0 = 0; k0 < 256; k0 += 32) {
        #pragma unroll
        for (int h = 0; h < 2; ++h) {
            int u = t + h * 256;
            int row = u >> 3;
            int kq = (u & 7) * 4;
            int grow = row0 + row;
            float4 v = make_float4(0.f, 0.f, 0.f, 0.f);
            if (grow < M) v = *reinterpret_cast<const float4*>(&X[(size_t)grow * 256 + k0 + kq]);
            uint lo = (uint)f2bf(v.x) | ((uint)f2bf(v.y) << 16);
            uint hi = (uint)f2bf(v.z) | ((uint)f2bf(v.w) << 16);
            *reinterpret_cast<uint2*>(&Xs[row * G1_STRIDE + kq]) = make_uint2(lo, hi);
        }
        #pragma unroll
        for (int h = 0; h < 4; ++h) {
            int u = t + h * 256;
            int n = u >> 2;
            int seg = u & 3;
            uint4 wv = *reinterpret_cast<const uint4*>(&W1T[(size_t)n * 256 + k0 + seg * 8]);
            *reinterpret_cast<uint4*>(&Ws[n * G1_STRIDE + seg * 8]) = wv;
        }
        __syncthreads();
        bf16x8 wf[4], xf[4];
        #pragma unroll
        for (int j = 0; j < 4; ++j)
            wf[j] = *reinterpret_cast<const bf16x8*>(&Ws[(w * 64 + j * 16 + lr) * G1_STRIDE + lg * 8]);
        #pragma unroll
        for (int i = 0; i < 4; ++i)
            xf[i] = *reinterpret_cast<const bf16x8*>(&Xs[(i * 16 + lr) * G1_STRIDE + lg * 8]);
        #pragma unroll
        for (int j = 0; j < 4; ++j)
            #pragma unroll
            for (int i = 0; i < 4; ++i)
                acc[j][i] = __builtin_amdgcn_mfma_f32_16x16x32_bf16(wf[j], xf[i], acc[j][i], 0, 0, 0);
        __syncthreads();
    }

    #pragma unroll
    for (int mi = 0; mi < 4; ++mi) {
        int grow = row0 + mi * 16 + lr;
        float dv = Dvs[mi * 16 + lr];
        bool ok = grow < M;
        #pragma unroll
        for (int nj = 0; nj < 4; ++nj) {
            f32x4 a = acc[nj][mi];
            uint lo = (uint)f2bf(a[0] * dv) | ((uint)f2bf(a[1] * dv) << 16);
            uint hi = (uint)f2bf(a[2] * dv) | ((uint)f2bf(a[3] * dv) << 16);
            if (ok) {
                int col = w * 64 + nj * 16 + lg * 4;
                *reinterpret_cast<uint2*>(&H1[(size_t)grow * 256 + col]) = make_uint2(lo, hi);
            }
        }
    }
}

// ---------- layer-1 aggregation (+b1, ELU) fused with GEMM2 (256->10) ----------
// one wave per node: 64 lanes x 4 features; H1 is pre-scaled by dinv[src].
// Edge segments are src-block-sorted (see scatter) for L2 temporal locality.
__global__ __launch_bounds__(256) void agg1_gemm2_kernel(
    const ushort* __restrict__ H1, const int* __restrict__ offs, const int* __restrict__ ssrc,
    const float* __restrict__ dinv, const float* __restrict__ b1, const float* __restrict__ W2,
    float* __restrict__ H2, int NN) {
    int lane = threadIdx.x & 63;
    int node = blockIdx.x * 4 + (threadIdx.x >> 6);
    if (node >= NN) return;
    int beg = offs[node], end = offs[node + 1];
    int col = lane * 4;
    const ushort* H1c = H1 + col;
    float acc0 = 0.f, acc1 = 0.f, acc2 = 0.f, acc3 = 0.f;
    int i = beg;
    for (; i + 3 < end; i += 4) {
        int s0 = ssrc[i], s1 = ssrc[i + 1], s2 = ssrc[i + 2], s3 = ssrc[i + 3];
        uint2 p0 = *reinterpret_cast<const uint2*>(H1c + (size_t)s0 * 256);
        uint2 p1 = *reinterpret_cast<const uint2*>(H1c + (size_t)s1 * 256);
        uint2 p2 = *reinterpret_cast<const uint2*>(H1c + (size_t)s2 * 256);
        uint2 p3 = *reinterpret_cast<const uint2*>(H1c + (size_t)s3 * 256);
        acc0 += bf2f_lo(p0.x) + bf2f_lo(p1.x) + bf2f_lo(p2.x) + bf2f_lo(p3.x);
        acc1 += bf2f_hi(p0.x) + bf2f_hi(p1.x) + bf2f_hi(p2.x) + bf2f_hi(p3.x);
        acc2 += bf2f_lo(p0.y) + bf2f_lo(p1.y) + bf2f_lo(p2.y) + bf2f_lo(p3.y);
        acc3 += bf2f_hi(p0.y) + bf2f_hi(p1.y) + bf2f_hi(p2.y) + bf2f_hi(p3.y);
    }
    for (; i < end; ++i) {
        int s = ssrc[i];
        uint2 p = *reinterpret_cast<const uint2*>(H1c + (size_t)s * 256);
        acc0 += bf2f_lo(p.x);
        acc1 += bf2f_hi(p.x);
        acc2 += bf2f_lo(p.y);
        acc3 += bf2f_hi(p.y);
    }
    {   // self loop
        uint2 p = *reinterpret_cast<const uint2*>(H1c + (size_t)node * 256);
        acc0 += bf2f_lo(p.x);
        acc1 += bf2f_hi(p.x);
        acc2 += bf2f_lo(p.y);
        acc3 += bf2f_hi(p.y);
    }
    float dn = dinv[node];
    float a0 = elu(fmaf(acc0, dn, b1[col + 0]));
    float a1 = elu(fmaf(acc1, dn, b1[col + 1]));
    float a2 = elu(fmaf(acc2, dn, b1[col + 2]));
    float a3 = elu(fmaf(acc3, dn, b1[col + 3]));
    float hv = 0.f;
    #pragma unroll
    for (int c = 0; c < 10; ++c) {
        float p = a0 * W2[(col + 0) * 10 + c]
                + a1 * W2[(col + 1) * 10 + c]
                + a2 * W2[(col + 2) * 10 + c]
                + a3 * W2[(col + 3) * 10 + c];
        #pragma unroll
        for (int m = 1; m < 64; m <<= 1) p += __shfl_xor(p, m, 64);
        if (lane == c) hv = p;
    }
    if (lane < 10) H2[(size_t)node * 10 + lane] = dn * hv;   // fold dinv[node] for layer 2
}

// ---------- layer-2 aggregation (+b2, ELU) -> per-node activations ----------
__global__ __launch_bounds__(256) void agg2_elu_kernel(
    const float* __restrict__ H2, const int* __restrict__ offs, const int* __restrict__ ssrc,
    const float* __restrict__ dinv, const float* __restrict__ b2,
    float* __restrict__ H2act, int NN) {
    int t = threadIdx.x;
    int node = blockIdx.x * 8 + (t >> 5);
    if (node >= NN) return;
    int sub = t & 31;
    int c = sub & 15;
    int e2 = sub >> 4;
    int beg = offs[node], end = offs[node + 1];
    float acc = 0.f;
    int i = beg + e2;
    for (; i + 6 < end; i += 8) {
        int s0 = ssrc[i], s1 = ssrc[i + 2], s2 = ssrc[i + 4], s3 = ssrc[i + 6];
        float h0 = H2[(size_t)s0 * 10 + c];
        float h1 = H2[(size_t)s1 * 10 + c];
        float h2 = H2[(size_t)s2 * 10 + c];
        float h3 = H2[(size_t)s3 * 10 + c];
        acc += (h0 + h1) + (h2 + h3);
    }
    for (; i < end; i += 2) acc += H2[(size_t)ssrc[i] * 10 + c];
    if (e2 == 0) acc += H2[(size_t)node * 10 + c];   // self loop (pre-scaled)
    acc += __shfl_xor(acc, 16, 64);
    if (sub < 10) {
        float dn = dinv[node];
        H2act[(size_t)node * 10 + c] = elu(fmaf(dn, acc, b2[c]));
    }
}

// ---------- per-graph mean pool + log_softmax (no atomics) ----------
__global__ __launch_bounds__(320) void pool_final_kernel(
    const float* __restrict__ H2act, const int* __restrict__ gstart,
    float* __restrict__ out, int NG) {
    __shared__ float red[32][10];
    __shared__ float m[10];
    __shared__ float s_lse;
    int g = blockIdx.x;
    int t = threadIdx.x;
    int grp = t / 10;
    int c = t - grp * 10;
    int lo = gstart[g], hi = gstart[g + 1];
    float acc = 0.f;
    if (grp < 32) {
        for (int n = lo + grp; n < hi; n += 32) acc += H2act[(size_t)n * 10 + c];
        red[grp][c] = acc;
    }
    __syncthreads();
    if (t < 10) {
        float s = 0.f;
        #pragma unroll
        for (int j = 0; j < 32; ++j) s += red[j][t];
        m[t] = s / fmaxf((float)(hi - lo), 1.0f);
    }
    __syncthreads();
    if (t == 0) {
        float mx = -1e30f;
        for (int c2 = 0; c2 < 10; ++c2) mx = fmaxf(mx, m[c2]);
        float s = 0.f;
        for (int c2 = 0; c2 < 10; ++c2) s += expf(m[c2] - mx);
        s_lse = logf(s) + mx;
    }
    __syncthreads();
    if (t < 10) out[g * 10 + t] = m[t] - s_lse;
}

extern "C" void kernel_launch(void* const* d_in, const int* in_sizes, int n_in,
                              void* d_out, int out_size, void* d_ws, size_t ws_size,
                              hipStream_t stream) {
    const float* x     = (const float*)d_in[0];
    const int*   eidx  = (const int*)d_in[1];
    const int*   batch = (const int*)d_in[2];
    const float* W1    = (const float*)d_in[3];
    const float* b1    = (const float*)d_in[4];
    const float* W2    = (const float*)d_in[5];
    const float* b2    = (const float*)d_in[6];

    int NN = in_sizes[0] / 256;     // 50000
    int E  = in_sizes[1] / 2;       // 1600000
    int NG = out_size / 10;         // 64
    const int* src = eidx;
    const int* dst = eidx + E;

    int M2 = NN * SBLK_STRIDE;      // bucketed counter count

    char* ws = (char*)d_ws;
    size_t off = 0;
    auto alloc = [&](size_t bytes) -> void* {
        void* p = ws + off;
        off += (bytes + 255) & ~((size_t)255);
        return p;
    };
    int*    cnt2     = (int*)alloc((size_t)M2 * 4);
    int*    offs2    = (int*)alloc((size_t)M2 * 4);
    int*    cursor2  = (int*)alloc((size_t)M2 * 4);
    int*    offs     = (int*)alloc((size_t)(NN + 1) * 4);
    int*    partials = (int*)alloc(4096 * 4);
    int*    pscan    = (int*)alloc(4096 * 4);
    float*  dinv     = (float*)alloc((size_t)NN * 4);
    int*    gstart   = (int*)alloc((size_t)(NG + 1) * 4);
    ushort* W1T      = (ushort*)alloc((size_t)256 * 256 * 2);
    int*    ssrc     = (int*)alloc((size_t)E * 4);
    ushort* H1       = (ushort*)alloc((size_t)NN * 256 * 2);
    float*  H2       = (float*)alloc((size_t)NN * 10 * 4);
    float*  H2act    = (float*)alloc((size_t)NN * 10 * 4);

    hipMemsetAsync(cnt2, 0, (size_t)M2 * 4, stream);

    int nb2 = (M2 + 255) / 256;     // 3125 <= 4096 (scan2 capacity)
    count2_kernel <<<1024, 256, 0, stream>>>(src, dst, E, cnt2);
    scan1_kernel  <<<nb2, 256, 0, stream>>>(cnt2, M2, partials);
    scan2_kernel  <<<1, 256, 0, stream>>>(partials, nb2, pscan);
    scan3_kernel  <<<nb2, 256, 0, stream>>>(cnt2, M2, pscan, offs2, cursor2);
    post_kernel   <<<(NN + 255) / 256, 256, 0, stream>>>(offs2, NN, E, offs, dinv);
    scatter_kernel<<<2048, 256, 0, stream>>>(src, dst, E, cursor2, ssrc, NN);
    gstart_kernel <<<1, 128, 0, stream>>>(batch, NN, NG, gstart);
    wtrans_kernel <<<16, 256, 0, stream>>>(W1, W1T);
    gemm1_mfma_kernel<<<(NN + 63) / 64, 256, 0, stream>>>(x, W1T, dinv, H1, NN);
    agg1_gemm2_kernel<<<(NN + 3) / 4, 256, 0, stream>>>(H1, offs, ssrc, dinv, b1, W2, H2, NN);
    agg2_elu_kernel  <<<(NN + 7) / 8, 256, 0, stream>>>(H2, offs, ssrc, dinv, b2, H2act, NN);
    pool_final_kernel<<<NG, 320, 0, stream>>>(H2act, gstart, (float*)d_out, NG);
}

// Round 7
// 308.715 us; speedup vs baseline: 1.6552x; 1.0929x over previous
//
#include <hip/hip_runtime.h>
#include <hip/hip_bf16.h>
#include <math.h>

typedef unsigned int uint;
typedef unsigned short ushort;
typedef unsigned char uchar;

typedef __attribute__((ext_vector_type(8))) short bf16x8;
typedef __attribute__((ext_vector_type(4))) float f32x4;
typedef __attribute__((ext_vector_type(2))) float f32x2;

// src-block sorting (kept from R6): edges within each dst segment bucketed by
// src>>12. H2 rows padded to 16 floats (one 64B line per gather).
#define SBLK_SHIFT 12
#define SBLK_STRIDE 16
#define H2S 16

// ---------- small helpers ----------
__device__ __forceinline__ ushort f2bf(float f) {
    uint u = __float_as_uint(f);
    uint rounding = 0x7fffu + ((u >> 16) & 1u);   // round-to-nearest-even
    return (ushort)((u + rounding) >> 16);
}
__device__ __forceinline__ float elu(float x) {
    return x > 0.f ? x : expm1f(x);
}

// ---------- per-(dst, src-block) histogram ----------
__global__ void count2_kernel(const int* __restrict__ src, const int* __restrict__ dst, int E,
                              int* __restrict__ cnt2) {
    int i = blockIdx.x * blockDim.x + threadIdx.x;
    int stride = gridDim.x * blockDim.x;
    for (; i < E; i += stride)
        atomicAdd(&cnt2[dst[i] * SBLK_STRIDE + (src[i] >> SBLK_SHIFT)], 1);
}

// ---------- exclusive scan over cnt2 (3-phase, M entries) ----------
__global__ void scan1_kernel(const int* __restrict__ cnt, int M, int* __restrict__ partials) {
    __shared__ int sh[256];
    int i = blockIdx.x * 256 + threadIdx.x;
    sh[threadIdx.x] = (i < M) ? cnt[i] : 0;
    __syncthreads();
    for (int s = 128; s > 0; s >>= 1) {
        if (threadIdx.x < s) sh[threadIdx.x] += sh[threadIdx.x + s];
        __syncthreads();
    }
    if (threadIdx.x == 0) partials[blockIdx.x] = sh[0];
}

// parallel exclusive scan of up to 4096 partials (256 thr x 16 each)
__global__ __launch_bounds__(256) void scan2_kernel(const int* __restrict__ partials, int nb,
                                                    int* __restrict__ pscan) {
    __shared__ int tsum[256];
    int t = threadIdx.x;
    int pref[16];
    int s = 0;
    #pragma unroll
    for (int j = 0; j < 16; ++j) {
        int idx = t * 16 + j;
        int v = (idx < nb) ? partials[idx] : 0;
        pref[j] = s;
        s += v;
    }
    tsum[t] = s;
    __syncthreads();
    for (int d = 1; d < 256; d <<= 1) {
        int x = (t >= d) ? tsum[t - d] : 0;
        __syncthreads();
        tsum[t] += x;
        __syncthreads();
    }
    int base = (t == 0) ? 0 : tsum[t - 1];
    #pragma unroll
    for (int j = 0; j < 16; ++j) {
        int idx = t * 16 + j;
        if (idx < nb) pscan[idx] = base + pref[j];
    }
}

__global__ void scan3_kernel(const int* __restrict__ cnt, int M, const int* __restrict__ pscan,
                             int* __restrict__ offs2, int* __restrict__ cursor2) {
    __shared__ int sh[256];
    int t = threadIdx.x;
    int i = blockIdx.x * 256 + t;
    int v = (i < M) ? cnt[i] : 0;
    sh[t] = v;
    __syncthreads();
    for (int d = 1; d < 256; d <<= 1) {
        int x = (t >= d) ? sh[t - d] : 0;
        __syncthreads();
        sh[t] += x;
        __syncthreads();
    }
    int excl = sh[t] - v;
    int base = pscan[blockIdx.x];
    if (i < M) {
        offs2[i]   = base + excl;
        cursor2[i] = base + excl;
    }
}

// ---------- per-node offsets + dinv from bucketed offsets ----------
__global__ void post_kernel(const int* __restrict__ offs2, int NN, int E,
                            int* __restrict__ offs, float* __restrict__ dinv) {
    int n = blockIdx.x * blockDim.x + threadIdx.x;
    if (n >= NN) return;
    int o = offs2[n * SBLK_STRIDE];
    int nxt = (n == NN - 1) ? E : offs2[(n + 1) * SBLK_STRIDE];
    offs[n] = o;
    dinv[n] = rsqrtf((float)(nxt - o) + 1.0f);
    if (n == NN - 1) offs[NN] = E;
}

// ---------- bucket edges by (dst, src-block), XCD-partitioned by dst ----------
__global__ __launch_bounds__(256) void scatter_kernel(const int* __restrict__ src,
                                                      const int* __restrict__ dst, int E,
                                                      int* __restrict__ cursor2,
                                                      int* __restrict__ ssrc, int NN) {
    int grp = blockIdx.x & 7;
    int per = (NN + 7) >> 3;
    int lo = grp * per;
    int hi = min(NN, lo + per);
    int bid = blockIdx.x >> 3;
    int nb  = gridDim.x >> 3;
    int i = bid * blockDim.x + threadIdx.x;
    int stride = nb * blockDim.x;
    for (; i < E; i += stride) {
        int d = dst[i];
        if (d >= lo && d < hi) {
            int s = src[i];
            int pos = atomicAdd(&cursor2[d * SBLK_STRIDE + (s >> SBLK_SHIFT)], 1);
            ssrc[pos] = s;
        }
    }
}

// ---------- graph boundaries via binary search on sorted batch ----------
__global__ void gstart_kernel(const int* __restrict__ batch, int NN, int NG,
                              int* __restrict__ gstart) {
    int g = blockIdx.x * blockDim.x + threadIdx.x;
    if (g > NG) return;
    int lo = 0, hi = NN;
    while (lo < hi) {
        int mid = (lo + hi) >> 1;
        if (batch[mid] < g) lo = mid + 1; else hi = mid;
    }
    gstart[g] = lo;
}

// ---------- W1T(bf16)[n][k] = W1[k][n], 64x64 tiles via LDS ----------
__global__ __launch_bounds__(256) void wtrans_kernel(const float* __restrict__ W,
                                                     ushort* __restrict__ WT) {
    __shared__ float T[64][68];
    int b = blockIdx.x;                 // 0..15
    int kt = (b >> 2) * 64, nt = (b & 3) * 64;
    int t = threadIdx.x;
    int r = t >> 4, c4 = (t & 15) * 4;
    #pragma unroll
    for (int h = 0; h < 4; ++h) {
        int rr = r + h * 16;
        float4 v = *reinterpret_cast<const float4*>(&W[(size_t)(kt + rr) * 256 + nt + c4]);
        *reinterpret_cast<float4*>(&T[rr][c4]) = v;
    }
    __syncthreads();
    int nr = t >> 2, ks = (t & 3) * 16;
    uint o[8];
    #pragma unroll
    for (int i = 0; i < 16; i += 2) {
        float f0 = T[ks + i][nr];
        float f1 = T[ks + i + 1][nr];
        o[i >> 1] = (uint)f2bf(f0) | ((uint)f2bf(f1) << 16);
    }
    size_t base = (size_t)(nt + nr) * 256 + kt + ks;
    *reinterpret_cast<uint4*>(&WT[base])     = make_uint4(o[0], o[1], o[2], o[3]);
    *reinterpret_cast<uint4*>(&WT[base + 8]) = make_uint4(o[4], o[5], o[6], o[7]);
}

// ---------- GEMM1 via MFMA: H1s(fp8 e4m3)[M,256] = dinv[m] * (X @ W1) ----------
#define G1_STRIDE 40   // ushorts per LDS row (80B = 20 banks; 16B-aligned frag reads)
__global__ __launch_bounds__(256) void gemm1_mfma_kernel(const float* __restrict__ X,
                                                         const ushort* __restrict__ W1T,
                                                         const float* __restrict__ dinv,
                                                         uchar* __restrict__ H1, int M) {
    __shared__ ushort Xs[64 * G1_STRIDE];
    __shared__ ushort Ws[256 * G1_STRIDE];
    __shared__ float  Dvs[64];
    int t = threadIdx.x;
    int row0 = blockIdx.x * 64;
    int lane = t & 63;
    int w = t >> 6;
    int lr = lane & 15;     // row/col within fragment
    int lg = lane >> 4;     // k-group (8 contiguous k per lane)

    if (t < 64) {
        int grow = row0 + t;
        Dvs[t] = (grow < M) ? dinv[grow] : 0.f;
    }

    f32x4 acc[4][4];
    #pragma unroll
    for (int j = 0; j < 4; ++j)
        #pragma unroll
        for (int i = 0; i < 4; ++i)
            acc[j][i] = (f32x4){0.f, 0.f, 0.f, 0.f};

    for (int k0 = 0; k0 < 256; k0 += 32) {
        #pragma unroll
        for (int h = 0; h < 2; ++h) {
            int u = t + h * 256;
            int row = u >> 3;
            int kq = (u & 7) * 4;
            int grow = row0 + row;
            float4 v = make_float4(0.f, 0.f, 0.f, 0.f);
            if (grow < M) v = *reinterpret_cast<const float4*>(&X[(size_t)grow * 256 + k0 + kq]);
            uint lo = (uint)f2bf(v.x) | ((uint)f2bf(v.y) << 16);
            uint hi = (uint)f2bf(v.z) | ((uint)f2bf(v.w) << 16);
            *reinterpret_cast<uint2*>(&Xs[row * G1_STRIDE + kq]) = make_uint2(lo, hi);
        }
        #pragma unroll
        for (int h = 0; h < 4; ++h) {
            int u = t + h * 256;
            int n = u >> 2;
            int seg = u & 3;
            uint4 wv = *reinterpret_cast<const uint4*>(&W1T[(size_t)n * 256 + k0 + seg * 8]);
            *reinterpret_cast<uint4*>(&Ws[n * G1_STRIDE + seg * 8]) = wv;
        }
        __syncthreads();
        bf16x8 wf[4], xf[4];
        #pragma unroll
        for (int j = 0; j < 4; ++j)
            wf[j] = *reinterpret_cast<const bf16x8*>(&Ws[(w * 64 + j * 16 + lr) * G1_STRIDE + lg * 8]);
        #pragma unroll
        for (int i = 0; i < 4; ++i)
            xf[i] = *reinterpret_cast<const bf16x8*>(&Xs[(i * 16 + lr) * G1_STRIDE + lg * 8]);
        #pragma unroll
        for (int j = 0; j < 4; ++j)
            #pragma unroll
            for (int i = 0; i < 4; ++i)
                acc[j][i] = __builtin_amdgcn_mfma_f32_16x16x32_bf16(wf[j], xf[i], acc[j][i], 0, 0, 0);
        __syncthreads();
    }

    // epilogue: scale by dinv[row], pack 4 f32 -> 4 fp8 e4m3 (one dword) per lane
    #pragma unroll
    for (int mi = 0; mi < 4; ++mi) {
        int grow = row0 + mi * 16 + lr;
        float dv = Dvs[mi * 16 + lr];
        bool ok = grow < M;
        #pragma unroll
        for (int nj = 0; nj < 4; ++nj) {
            f32x4 a = acc[nj][mi];
            int pk = __builtin_amdgcn_cvt_pk_fp8_f32(a[0] * dv, a[1] * dv, 0, false);
            pk     = __builtin_amdgcn_cvt_pk_fp8_f32(a[2] * dv, a[3] * dv, pk, true);
            if (ok) {
                int col = w * 64 + nj * 16 + lg * 4;
                *reinterpret_cast<uint*>(&H1[(size_t)grow * 256 + col]) = (uint)pk;
            }
        }
    }
}

// ---------- layer-1 aggregation (+b1, ELU) fused with GEMM2 (256->10) ----------
// one wave per node: 64 lanes x 4 features; H1 is fp8 e4m3, pre-scaled by
// dinv[src]. Row = 256B -> one dword per lane per edge.
__global__ __launch_bounds__(256) void agg1_gemm2_kernel(
    const uchar* __restrict__ H1, const int* __restrict__ offs, const int* __restrict__ ssrc,
    const float* __restrict__ dinv, const float* __restrict__ b1, const float* __restrict__ W2,
    float* __restrict__ H2, int NN) {
    int lane = threadIdx.x & 63;
    int node = blockIdx.x * 4 + (threadIdx.x >> 6);
    if (node >= NN) return;
    int beg = offs[node], end = offs[node + 1];
    int col = lane * 4;
    const uchar* H1c = H1 + col;
    float acc0 = 0.f, acc1 = 0.f, acc2 = 0.f, acc3 = 0.f;
    int i = beg;
    for (; i + 3 < end; i += 4) {
        int s0 = ssrc[i], s1 = ssrc[i + 1], s2 = ssrc[i + 2], s3 = ssrc[i + 3];
        uint p0 = *reinterpret_cast<const uint*>(H1c + (size_t)s0 * 256);
        uint p1 = *reinterpret_cast<const uint*>(H1c + (size_t)s1 * 256);
        uint p2 = *reinterpret_cast<const uint*>(H1c + (size_t)s2 * 256);
        uint p3 = *reinterpret_cast<const uint*>(H1c + (size_t)s3 * 256);
        f32x2 l0 = __builtin_amdgcn_cvt_pk_f32_fp8((int)p0, false);
        f32x2 h0 = __builtin_amdgcn_cvt_pk_f32_fp8((int)p0, true);
        f32x2 l1 = __builtin_amdgcn_cvt_pk_f32_fp8((int)p1, false);
        f32x2 h1 = __builtin_amdgcn_cvt_pk_f32_fp8((int)p1, true);
        f32x2 l2 = __builtin_amdgcn_cvt_pk_f32_fp8((int)p2, false);
        f32x2 h2 = __builtin_amdgcn_cvt_pk_f32_fp8((int)p2, true);
        f32x2 l3 = __builtin_amdgcn_cvt_pk_f32_fp8((int)p3, false);
        f32x2 h3 = __builtin_amdgcn_cvt_pk_f32_fp8((int)p3, true);
        acc0 += (l0.x + l1.x) + (l2.x + l3.x);
        acc1 += (l0.y + l1.y) + (l2.y + l3.y);
        acc2 += (h0.x + h1.x) + (h2.x + h3.x);
        acc3 += (h0.y + h1.y) + (h2.y + h3.y);
    }
    for (; i < end; ++i) {
        int s = ssrc[i];
        uint p = *reinterpret_cast<const uint*>(H1c + (size_t)s * 256);
        f32x2 l = __builtin_amdgcn_cvt_pk_f32_fp8((int)p, false);
        f32x2 h = __builtin_amdgcn_cvt_pk_f32_fp8((int)p, true);
        acc0 += l.x; acc1 += l.y; acc2 += h.x; acc3 += h.y;
    }
    {   // self loop
        uint p = *reinterpret_cast<const uint*>(H1c + (size_t)node * 256);
        f32x2 l = __builtin_amdgcn_cvt_pk_f32_fp8((int)p, false);
        f32x2 h = __builtin_amdgcn_cvt_pk_f32_fp8((int)p, true);
        acc0 += l.x; acc1 += l.y; acc2 += h.x; acc3 += h.y;
    }
    float dn = dinv[node];
    float a0 = elu(fmaf(acc0, dn, b1[col + 0]));
    float a1 = elu(fmaf(acc1, dn, b1[col + 1]));
    float a2 = elu(fmaf(acc2, dn, b1[col + 2]));
    float a3 = elu(fmaf(acc3, dn, b1[col + 3]));
    float hv = 0.f;
    #pragma unroll
    for (int c = 0; c < 10; ++c) {
        float p = a0 * W2[(col + 0) * 10 + c]
                + a1 * W2[(col + 1) * 10 + c]
                + a2 * W2[(col + 2) * 10 + c]
                + a3 * W2[(col + 3) * 10 + c];
        #pragma unroll
        for (int m = 1; m < 64; m <<= 1) p += __shfl_xor(p, m, 64);
        if (lane == c) hv = p;
    }
    if (lane < 10) H2[(size_t)node * H2S + lane] = dn * hv;   // fold dinv[node]
}

// ---------- layer-2 aggregation (+b2, ELU) -> per-node activations ----------
// H2 rows padded to 16 floats: each random gather hits exactly one 64B line.
__global__ __launch_bounds__(256) void agg2_elu_kernel(
    const float* __restrict__ H2, const int* __restrict__ offs, const int* __restrict__ ssrc,
    const float* __restrict__ dinv, const float* __restrict__ b2,
    float* __restrict__ H2act, int NN) {
    int t = threadIdx.x;
    int node = blockIdx.x * 8 + (t >> 5);
    if (node >= NN) return;
    int sub = t & 31;
    int c = sub & 15;
    int e2 = sub >> 4;
    int beg = offs[node], end = offs[node + 1];
    float acc = 0.f;
    int i = beg + e2;
    for (; i + 6 < end; i += 8) {
        int s0 = ssrc[i], s1 = ssrc[i + 2], s2 = ssrc[i + 4], s3 = ssrc[i + 6];
        float h0 = H2[(size_t)s0 * H2S + c];
        float h1 = H2[(size_t)s1 * H2S + c];
        float h2 = H2[(size_t)s2 * H2S + c];
        float h3 = H2[(size_t)s3 * H2S + c];
        acc += (h0 + h1) + (h2 + h3);
    }
    for (; i < end; i += 2) acc += H2[(size_t)ssrc[i] * H2S + c];
    if (e2 == 0) acc += H2[(size_t)node * H2S + c];   // self loop (pre-scaled)
    acc += __shfl_xor(acc, 16, 64);
    if (sub < 10) {
        float dn = dinv[node];
        H2act[(size_t)node * 10 + c] = elu(fmaf(dn, acc, b2[c]));
    }
}

// ---------- per-graph mean pool + log_softmax (no atomics) ----------
__global__ __launch_bounds__(320) void pool_final_kernel(
    const float* __restrict__ H2act, const int* __restrict__ gstart,
    float* __restrict__ out, int NG) {
    __shared__ float red[32][10];
    __shared__ float m[10];
    __shared__ float s_lse;
    int g = blockIdx.x;
    int t = threadIdx.x;
    int grp = t / 10;
    int c = t - grp * 10;
    int lo = gstart[g], hi = gstart[g + 1];
    float acc = 0.f;
    if (grp < 32) {
        for (int n = lo + grp; n < hi; n += 32) acc += H2act[(size_t)n * 10 + c];
        red[grp][c] = acc;
    }
    __syncthreads();
    if (t < 10) {
        float s = 0.f;
        #pragma unroll
        for (int j = 0; j < 32; ++j) s += red[j][t];
        m[t] = s / fmaxf((float)(hi - lo), 1.0f);
    }
    __syncthreads();
    if (t == 0) {
        float mx = -1e30f;
        for (int c2 = 0; c2 < 10; ++c2) mx = fmaxf(mx, m[c2]);
        float s = 0.f;
        for (int c2 = 0; c2 < 10; ++c2) s += expf(m[c2] - mx);
        s_lse = logf(s) + mx;
    }
    __syncthreads();
    if (t < 10) out[g * 10 + t] = m[t] - s_lse;
}

extern "C" void kernel_launch(void* const* d_in, const int* in_sizes, int n_in,
                              void* d_out, int out_size, void* d_ws, size_t ws_size,
                              hipStream_t stream) {
    const float* x     = (const float*)d_in[0];
    const int*   eidx  = (const int*)d_in[1];
    const int*   batch = (const int*)d_in[2];
    const float* W1    = (const float*)d_in[3];
    const float* b1    = (const float*)d_in[4];
    const float* W2    = (const float*)d_in[5];
    const float* b2    = (const float*)d_in[6];

    int NN = in_sizes[0] / 256;     // 50000
    int E  = in_sizes[1] / 2;       // 1600000
    int NG = out_size / 10;         // 64
    const int* src = eidx;
    const int* dst = eidx + E;

    int M2 = NN * SBLK_STRIDE;      // bucketed counter count

    char* ws = (char*)d_ws;
    size_t off = 0;
    auto alloc = [&](size_t bytes) -> void* {
        void* p = ws + off;
        off += (bytes + 255) & ~((size_t)255);
        return p;
    };
    int*    cnt2     = (int*)alloc((size_t)M2 * 4);
    int*    offs2    = (int*)alloc((size_t)M2 * 4);
    int*    cursor2  = (int*)alloc((size_t)M2 * 4);
    int*    offs     = (int*)alloc((size_t)(NN + 1) * 4);
    int*    partials = (int*)alloc(4096 * 4);
    int*    pscan    = (int*)alloc(4096 * 4);
    float*  dinv     = (float*)alloc((size_t)NN * 4);
    int*    gstart   = (int*)alloc((size_t)(NG + 1) * 4);
    ushort* W1T      = (ushort*)alloc((size_t)256 * 256 * 2);
    int*    ssrc     = (int*)alloc((size_t)E * 4);
    uchar*  H1       = (uchar*)alloc((size_t)NN * 256);
    float*  H2       = (float*)alloc((size_t)NN * H2S * 4);
    float*  H2act    = (float*)alloc((size_t)NN * 10 * 4);

    hipMemsetAsync(cnt2, 0, (size_t)M2 * 4, stream);

    int nb2 = (M2 + 255) / 256;     // 3125 <= 4096 (scan2 capacity)
    count2_kernel <<<1024, 256, 0, stream>>>(src, dst, E, cnt2);
    scan1_kernel  <<<nb2, 256, 0, stream>>>(cnt2, M2, partials);
    scan2_kernel  <<<1, 256, 0, stream>>>(partials, nb2, pscan);
    scan3_kernel  <<<nb2, 256, 0, stream>>>(cnt2, M2, pscan, offs2, cursor2);
    post_kernel   <<<(NN + 255) / 256, 256, 0, stream>>>(offs2, NN, E, offs, dinv);
    scatter_kernel<<<2048, 256, 0, stream>>>(src, dst, E, cursor2, ssrc, NN);
    gstart_kernel <<<1, 128, 0, stream>>>(batch, NN, NG, gstart);
    wtrans_kernel <<<16, 256, 0, stream>>>(W1, W1T);
    gemm1_mfma_kernel<<<(NN + 63) / 64, 256, 0, stream>>>(x, W1T, dinv, H1, NN);
    agg1_gemm2_kernel<<<(NN + 3) / 4, 256, 0, stream>>>(H1, offs, ssrc, dinv, b1, W2, H2, NN);
    agg2_elu_kernel  <<<(NN + 7) / 8, 256, 0, stream>>>(H2, offs, ssrc, dinv, b2, H2act, NN);
    pool_final_kernel<<<NG, 320, 0, stream>>>(H2act, gstart, (float*)d_out, NG);
}